// Round 1
// baseline (56.699 us; speedup 1.0000x reference)
//
#include <hip/hip_runtime.h>

// ---------------------------------------------------------------------------
// Builder: compute M[i][j][k] = Re( V^dag Z_i V )[j][k]  (4 x 16 x 16 floats)
// where V is the fixed variational unitary (3 layers of Rot + CNOT ring).
// Wire w <-> bit (3-w) of the flattened index (wire 0 = MSB).
// ---------------------------------------------------------------------------
__global__ void build_M_kernel(const float* __restrict__ w, float* __restrict__ Mout) {
    __shared__ float Vr[16][17];
    __shared__ float Vi[16][17];
    int t = threadIdx.x;
    if (t < 16) {
        float vr[16], vi[16];
        #pragma unroll
        for (int m = 0; m < 16; ++m) { vr[m] = (m == t) ? 1.f : 0.f; vi[m] = 0.f; }
        for (int L = 0; L < 3; ++L) {
            for (int q = 0; q < 4; ++q) {
                float phi = w[L * 12 + q * 3 + 0];
                float th  = w[L * 12 + q * 3 + 1];
                float om  = w[L * 12 + q * 3 + 2];
                float ct = cosf(0.5f * th), st = sinf(0.5f * th);
                float a  = 0.5f * (phi + om), d = 0.5f * (phi - om);
                float ca = cosf(a), sa = sinf(a), cd = cosf(d), sd = sinf(d);
                // Rot = RZ(om) RY(th) RZ(phi):
                // U00 = ct*e^{-ia}  U01 = -st*e^{+id}
                // U10 = st*e^{-id}  U11 = ct*e^{+ia}
                float u00r =  ct * ca, u00i = -ct * sa;
                float u01r = -st * cd, u01i = -st * sd;
                float u10r =  st * cd, u10i = -st * sd;
                float u11r =  ct * ca, u11i =  ct * sa;
                int mask = 8 >> q;
                #pragma unroll
                for (int idx = 0; idx < 16; ++idx) {
                    if (idx & mask) continue;
                    int hi = idx | mask;
                    float ar = vr[idx], ai = vi[idx];
                    float br = vr[hi],  bi = vi[hi];
                    vr[idx] = u00r * ar - u00i * ai + u01r * br - u01i * bi;
                    vi[idx] = u00r * ai + u00i * ar + u01r * bi + u01i * br;
                    vr[hi]  = u10r * ar - u10i * ai + u11r * br - u11i * bi;
                    vi[hi]  = u10r * ai + u10i * ar + u11r * bi + u11i * br;
                }
            }
            #pragma unroll
            for (int q = 0; q < 4; ++q) {
                int cm = 8 >> q;
                int tm = 8 >> ((q + 1) & 3);
                #pragma unroll
                for (int idx = 0; idx < 16; ++idx) {
                    if ((idx & cm) && !(idx & tm)) {
                        int o = idx | tm;
                        float tr = vr[idx], ti = vi[idx];
                        vr[idx] = vr[o]; vi[idx] = vi[o];
                        vr[o] = tr;      vi[o] = ti;
                    }
                }
            }
        }
        #pragma unroll
        for (int m = 0; m < 16; ++m) { Vr[m][t] = vr[m]; Vi[m][t] = vi[m]; }
    }
    __syncthreads();
    // M_i[j][k] = sum_m z_i(m) * (Vr[m][j]Vr[m][k] + Vi[m][j]Vi[m][k])
    for (int e = t; e < 1024; e += 64) {
        int i = e >> 8, j = (e >> 4) & 15, k = e & 15;
        float acc = 0.f;
        #pragma unroll
        for (int m = 0; m < 16; ++m) {
            float term = Vr[m][j] * Vr[m][k] + Vi[m][j] * Vi[m][k];
            acc += ((m >> (3 - i)) & 1) ? -term : term;
        }
        Mout[e] = acc;
    }
}

// ---------------------------------------------------------------------------
// Fused main kernel: 64 threads (1 wave) per block, 64 rows per block,
// one row per thread.
// ---------------------------------------------------------------------------
__global__ __launch_bounds__(64) void qffn_kernel(
        const float* __restrict__ x,
        const float* __restrict__ W_in,
        const float* __restrict__ b_in,
        const float* __restrict__ W_out,
        const float* __restrict__ b_out,
        const float* __restrict__ Mg,
        float* __restrict__ out,
        int nrows) {
    __shared__ float xt[64][33];                    // x tile chunk, stride 33: conflict-free col reads
    __shared__ __align__(16) float Ms[4][16][16];   // the 4 quadratic-form matrices
    __shared__ __align__(16) float Wt[64][4];       // W_in transposed: Wt[j][i]
    __shared__ float qs[64][5];                     // per-row <Z_i>, padded stride 5
    const int t = threadIdx.x;
    const long rbase = (long)blockIdx.x * 64;
    if (rbase >= nrows) return;

    // ---- stage constants (broadcast-read later) ----
    {
        const float4* m4 = (const float4*)Mg;
        float4* md = (float4*)&Ms[0][0][0];
        #pragma unroll
        for (int it = 0; it < 4; ++it) md[it * 64 + t] = m4[it * 64 + t];
        #pragma unroll
        for (int it = 0; it < 4; ++it) Wt[t][it] = W_in[it * 64 + t];   // Wt[j][i] = W_in[i*64+j]
    }
    float acc0 = b_in[0], acc1 = b_in[1], acc2 = b_in[2], acc3 = b_in[3];

    // ---- projection: two 64x32 chunks staged through LDS ----
    #pragma unroll
    for (int ch = 0; ch < 2; ++ch) {
        __syncthreads();
        #pragma unroll
        for (int it = 0; it < 8; ++it) {
            int f = it * 64 + t;            // float4 index in [0,512)
            int row = f >> 3, cf = f & 7;   // row in tile, float4-col in chunk
            long gr = rbase + row;
            if (gr >= nrows) gr = nrows - 1;
            float4 v = *(const float4*)(x + gr * 64 + ch * 32 + cf * 4);
            float* dst = &xt[row][cf * 4];
            dst[0] = v.x; dst[1] = v.y; dst[2] = v.z; dst[3] = v.w;
        }
        __syncthreads();
        #pragma unroll
        for (int j = 0; j < 32; ++j) {
            float xv = xt[t][j];
            float4 w4 = *(const float4*)&Wt[ch * 32 + j][0];  // broadcast
            acc0 += xv * w4.x; acc1 += xv * w4.y;
            acc2 += xv * w4.z; acc3 += xv * w4.w;
        }
    }

    // ---- tanh -> angles -> half-angle trig ----
    const float PI = 3.14159265358979323846f;
    float e0 = __expf(2.f * acc0), e1 = __expf(2.f * acc1);
    float e2 = __expf(2.f * acc2), e3 = __expf(2.f * acc3);
    float p0 = 1.f - 2.f / (e0 + 1.f), p1 = 1.f - 2.f / (e1 + 1.f);
    float p2 = 1.f - 2.f / (e2 + 1.f), p3 = 1.f - 2.f / (e3 + 1.f);
    float h0 = 0.5f * PI * p0, h1 = 0.5f * PI * p1;
    float h2 = 0.5f * PI * p2, h3 = 0.5f * PI * p3;
    float cs0 = __cosf(h0), sn0 = __sinf(h0);
    float cs1 = __cosf(h1), sn1 = __sinf(h1);
    float cs2 = __cosf(h2), sn2 = __sinf(h2);
    float cs3 = __cosf(h3), sn3 = __sinf(h3);

    // ---- separable state s = v0 (x) v1 (x) v2 (x) v3 ----
    float pA[4] = { cs0 * cs1, cs0 * sn1, sn0 * cs1, sn0 * sn1 };
    float pB[4] = { cs2 * cs3, cs2 * sn3, sn2 * cs3, sn2 * sn3 };
    float s[16];
    #pragma unroll
    for (int idx = 0; idx < 16; ++idx)
        s[idx] = pA[idx >> 2] * pB[idx & 3];

    // ---- ev_i = s^T M_i s  (M reads are wave-uniform broadcasts) ----
    float ev[4];
    #pragma unroll
    for (int i = 0; i < 4; ++i) {
        float acc = 0.f;
        #pragma unroll
        for (int j = 0; j < 16; ++j) {
            const float4* mr = (const float4*)&Ms[i][j][0];
            float4 m0 = mr[0], m1 = mr[1], m2 = mr[2], m3 = mr[3];
            float d = m0.x * s[0]  + m0.y * s[1]  + m0.z * s[2]  + m0.w * s[3]
                    + m1.x * s[4]  + m1.y * s[5]  + m1.z * s[6]  + m1.w * s[7]
                    + m2.x * s[8]  + m2.y * s[9]  + m2.z * s[10] + m2.w * s[11]
                    + m3.x * s[12] + m3.y * s[13] + m3.z * s[14] + m3.w * s[15];
            acc += d * s[j];
        }
        ev[i] = acc;
    }
    qs[t][0] = ev[0]; qs[t][1] = ev[1]; qs[t][2] = ev[2]; qs[t][3] = ev[3];
    __syncthreads();

    // ---- output projection, cooperatively: thread t owns 4 contiguous cols ----
    int cg = (t & 15) << 2;   // column group
    int r0 = t >> 4;          // row phase 0..3
    float4 wo0 = *(const float4*)(W_out + (cg + 0) * 4);
    float4 wo1 = *(const float4*)(W_out + (cg + 1) * 4);
    float4 wo2 = *(const float4*)(W_out + (cg + 2) * 4);
    float4 wo3 = *(const float4*)(W_out + (cg + 3) * 4);
    float4 bo  = *(const float4*)(b_out + cg);
    #pragma unroll
    for (int k = 0; k < 16; ++k) {
        int rr = (k << 2) + r0;
        float q0 = qs[rr][0], q1 = qs[rr][1], q2 = qs[rr][2], q3 = qs[rr][3];
        float4 o;
        o.x = bo.x + q0 * wo0.x + q1 * wo0.y + q2 * wo0.z + q3 * wo0.w;
        o.y = bo.y + q0 * wo1.x + q1 * wo1.y + q2 * wo1.z + q3 * wo1.w;
        o.z = bo.z + q0 * wo2.x + q1 * wo2.y + q2 * wo2.z + q3 * wo2.w;
        o.w = bo.w + q0 * wo3.x + q1 * wo3.y + q2 * wo3.z + q3 * wo3.w;
        long gr = rbase + rr;
        if (gr < nrows) *(float4*)(out + gr * 64 + cg) = o;
    }
}

extern "C" void kernel_launch(void* const* d_in, const int* in_sizes, int n_in,
                              void* d_out, int out_size, void* d_ws, size_t ws_size,
                              hipStream_t stream) {
    const float* x       = (const float*)d_in[0];
    const float* W_in    = (const float*)d_in[1];
    const float* b_in    = (const float*)d_in[2];
    const float* weights = (const float*)d_in[3];
    const float* W_out   = (const float*)d_in[4];
    const float* b_out   = (const float*)d_in[5];
    float* out = (float*)d_out;
    float* M   = (float*)d_ws;   // 4*16*16 floats = 4 KB

    int nrows = in_sizes[0] / 64;           // x is (N, 64)
    int nblk  = (nrows + 63) / 64;

    hipLaunchKernelGGL(build_M_kernel, dim3(1), dim3(64), 0, stream, weights, M);
    hipLaunchKernelGGL(qffn_kernel, dim3(nblk), dim3(64), 0, stream,
                       x, W_in, b_in, W_out, b_out, M, out, nrows);
}